// Round 2
// baseline (265.018 us; speedup 1.0000x reference)
//
#include <hip/hip_runtime.h>
#include <math.h>

// Shapes
#define Bn 256
#define Tn 64
#define Kn 49
#define Hn 512
#define An 49

// Workspace layout (floats):
//   cv : Bn*Kn*An = 614656   @ 0
//   cg : Bn*Tn*An = 802816   @ 614656
//   cs : Bn*Tn*An = 802816   @ 1417472
// total 2220288 floats = 8.9 MB
#define WS_CV 0
#define WS_CG 614656
#define WS_CS 1417472

// Output layout (floats):
//   c_hat : Bn*Tn*Hn = 8388608 @ 0
//   alpha : Bn*Tn*Kn = 802816  @ 8388608
//   beta  : Bn*Tn    = 16384   @ 9191424
#define OUT_ALPHA 8388608
#define OUT_BETA  9191424

__device__ __forceinline__ float fast_tanh(float x) {
    // tanh(x) = 1 - 2/(exp(2x)+1); saturates correctly for large |x|
    float e = __expf(2.0f * x);
    return 1.0f - 2.0f / (e + 1.0f);
}

// ---------------------------------------------------------------------------
// Kernel 1: three per-batch GEMMs vs H=512 reduction.
//   part 0: cv[b][k][a] = sum_h V[b,k,h]   * Wv[a,h]   (R=49)
//   part 1: cg[b][t][a] = sum_h h_t[b,t,h] * Wg[a,h]   (R=64)
//   part 2: cs[b][t][a] = sum_h s_t[b,t,h] * Ws[a,h]   (R=64)
// 256 threads, 16x16 thread grid, 4x4 register tile over 64x64 output slots.
// ---------------------------------------------------------------------------
__global__ __launch_bounds__(256) void gemm3_kernel(
    const float* __restrict__ V, const float* __restrict__ h_t,
    const float* __restrict__ s_t, const float* __restrict__ Wv,
    const float* __restrict__ Wg, const float* __restrict__ Ws,
    float* __restrict__ ws)
{
    const int b = blockIdx.x;
    const int part = blockIdx.y;

    const float* A;
    const float* W;
    float* out;
    int R;
    if (part == 0)      { A = V   + (size_t)b*Kn*Hn; W = Wv; out = ws + WS_CV + (size_t)b*Kn*An; R = Kn; }
    else if (part == 1) { A = h_t + (size_t)b*Tn*Hn; W = Wg; out = ws + WS_CG + (size_t)b*Tn*An; R = Tn; }
    else                { A = s_t + (size_t)b*Tn*Hn; W = Ws; out = ws + WS_CS + (size_t)b*Tn*An; R = Tn; }

    __shared__ float2 As[64][17];   // [row][float2-col], CH=32 -> 16 float2 + pad
    __shared__ float2 Wt[64][17];

    const int tid = threadIdx.x;
    const int ty = tid >> 4;       // 0..15
    const int tx = tid & 15;       // 0..15

    float acc[4][4] = {};

    const int lrow = tid >> 4;     // load row within a pass (0..15)
    const int lcol = tid & 15;     // load float2 col (0..15)

    for (int h0 = 0; h0 < Hn; h0 += 32) {
        __syncthreads();
        #pragma unroll
        for (int p = 0; p < 4; ++p) {
            int r = lrow + 16*p;
            float2 va = make_float2(0.f, 0.f);
            float2 vw = make_float2(0.f, 0.f);
            if (r < R)  va = *(const float2*)(A + (size_t)r*Hn + h0 + 2*lcol);
            if (r < An) vw = *(const float2*)(W + (size_t)r*Hn + h0 + 2*lcol);
            As[r][lcol] = va;
            Wt[r][lcol] = vw;
        }
        __syncthreads();
        #pragma unroll
        for (int c = 0; c < 16; ++c) {
            float2 av[4], wv[4];
            #pragma unroll
            for (int j = 0; j < 4; ++j) av[j] = As[ty + 16*j][c];
            #pragma unroll
            for (int i = 0; i < 4; ++i) wv[i] = Wt[tx + 16*i][c];
            #pragma unroll
            for (int j = 0; j < 4; ++j) {
                #pragma unroll
                for (int i = 0; i < 4; ++i) {
                    acc[j][i] += av[j].x * wv[i].x;
                    acc[j][i] += av[j].y * wv[i].y;
                }
            }
        }
    }

    #pragma unroll
    for (int j = 0; j < 4; ++j) {
        int k = ty + 16*j;
        if (k >= R) continue;
        #pragma unroll
        for (int i = 0; i < 4; ++i) {
            int a = tx + 16*i;
            if (a < An) out[(size_t)k*An + a] = acc[j][i];
        }
    }
}

// ---------------------------------------------------------------------------
// Kernel 2: fused tanh-score + softmax + c_t + c_hat per (b, 8-row t-tile).
// grid = 2048 blocks (256 b * 8 tiles), 256 threads (4 waves).
// ---------------------------------------------------------------------------
__global__ __launch_bounds__(256) void fused_kernel(
    const float* __restrict__ V, const float* __restrict__ s_t,
    const float* __restrict__ Wh, const float* __restrict__ ws,
    float* __restrict__ out)
{
    const int bid = blockIdx.x;
    const int b  = bid >> 3;
    const int t0 = (bid & 7) * 8;

    __shared__ float cv[49][49];   // stride 49 (odd) -> bank-conflict-free
    __shared__ float gl[8][49];
    __shared__ float cl[8][49];
    __shared__ float wh[49];
    __shared__ float zl[8][50];
    __shared__ float al[8][49];
    __shared__ float bl[8];

    const int tid = threadIdx.x;

    // stage cv[b], g rows, cs rows, Wh
    {
        const float* cvg = ws + WS_CV + (size_t)b*Kn*An;
        float* cvf = &cv[0][0];
        for (int i = tid; i < Kn*An; i += 256) cvf[i] = cvg[i];
        const float* cgg = ws + WS_CG + ((size_t)b*Tn + t0)*An;
        const float* csg = ws + WS_CS + ((size_t)b*Tn + t0)*An;
        float* gf = &gl[0][0];
        float* cf = &cl[0][0];
        for (int i = tid; i < 8*An; i += 256) { gf[i] = cgg[i]; cf[i] = csg[i]; }
        if (tid < An) wh[tid] = Wh[tid];
    }
    __syncthreads();

    // z phase: 392 (t,k) scores + 8 extended scores
    for (int idx = tid; idx < 400; idx += 256) {
        if (idx < 392) {
            const int tt = idx / 49;
            const int k  = idx % 49;
            float acc = 0.f;
            #pragma unroll 7
            for (int a = 0; a < 49; ++a)
                acc += fast_tanh(gl[tt][a] + cv[k][a]) * wh[a];
            zl[tt][k] = acc;
        } else {
            const int tt = idx - 392;
            float acc = 0.f;
            #pragma unroll 7
            for (int a = 0; a < 49; ++a)
                acc += fast_tanh(gl[tt][a] + cl[tt][a]) * wh[a];
            zl[tt][49] = acc;
        }
    }
    __syncthreads();

    // softmax: wave w handles rows 2w and 2w+1
    {
        const int w    = tid >> 6;
        const int lane = tid & 63;
        for (int rr = 0; rr < 2; ++rr) {
            const int row = w*2 + rr;
            float v = (lane < 49) ? zl[row][lane] : -1e30f;
            float m = v;
            #pragma unroll
            for (int o = 32; o; o >>= 1) m = fmaxf(m, __shfl_xor(m, o, 64));
            float e = (lane < 49) ? __expf(v - m) : 0.f;
            float s = e;
            #pragma unroll
            for (int o = 32; o; o >>= 1) s += __shfl_xor(s, o, 64);
            const float ze = zl[row][49];
            const float m2 = fmaxf(m, ze);
            const float eze = __expf(ze - m2);
            const float denom = s * __expf(m - m2) + eze;
            const float beta = eze / denom;
            if (lane < 49) {
                const float a = e / s;
                al[row][lane] = a;
                out[OUT_ALPHA + ((size_t)(b*Tn + t0 + row))*Kn + lane] = a;
            }
            if (lane == 0) {
                bl[row] = beta;
                out[OUT_BETA + (b*Tn + t0 + row)] = beta;
            }
        }
    }
    __syncthreads();

    // c_t + c_hat: thread = (tt = tid/32, 32-lane group over H via float4)
    {
        const int tt  = tid >> 5;
        const int l32 = tid & 31;
        const float* vb = V + (size_t)b*Kn*Hn;
        float4 acc[4] = {};
        for (int k = 0; k < 49; ++k) {
            const float ak = al[tt][k];
            const float4* vr = (const float4*)(vb + (size_t)k*Hn);
            #pragma unroll
            for (int j = 0; j < 4; ++j) {
                float4 vv = vr[l32 + 32*j];
                acc[j].x += ak*vv.x; acc[j].y += ak*vv.y;
                acc[j].z += ak*vv.z; acc[j].w += ak*vv.w;
            }
        }
        const float beta = bl[tt];
        const float omb  = 1.f - beta;
        const float4* sr = (const float4*)(s_t + ((size_t)b*Tn + t0 + tt)*Hn);
        float4* orow = (float4*)(out + ((size_t)b*Tn + t0 + tt)*Hn);
        #pragma unroll
        for (int j = 0; j < 4; ++j) {
            float4 sv = sr[l32 + 32*j];
            float4 o;
            o.x = beta*sv.x + omb*acc[j].x;
            o.y = beta*sv.y + omb*acc[j].y;
            o.z = beta*sv.z + omb*acc[j].z;
            o.w = beta*sv.w + omb*acc[j].w;
            orow[l32 + 32*j] = o;
        }
    }
}

extern "C" void kernel_launch(void* const* d_in, const int* in_sizes, int n_in,
                              void* d_out, int out_size, void* d_ws, size_t ws_size,
                              hipStream_t stream)
{
    const float* V   = (const float*)d_in[0];
    const float* h_t = (const float*)d_in[1];
    const float* s_t = (const float*)d_in[2];
    const float* Wv  = (const float*)d_in[3];
    const float* Wg  = (const float*)d_in[4];
    const float* Ws  = (const float*)d_in[5];
    const float* Wh  = (const float*)d_in[6];
    float* out = (float*)d_out;
    float* ws  = (float*)d_ws;   // needs 8.9 MB

    dim3 g1(Bn, 3);
    gemm3_kernel<<<g1, 256, 0, stream>>>(V, h_t, s_t, Wv, Wg, Ws, ws);
    fused_kernel<<<Bn*8, 256, 0, stream>>>(V, s_t, Wh, ws, out);
}

// Round 3
// 213.032 us; speedup vs baseline: 1.2440x; 1.2440x over previous
//
#include <hip/hip_runtime.h>
#include <hip/hip_bf16.h>
#include <math.h>

// Shapes
#define Bn 256
#define Tn 64
#define Kn 49
#define Hn 512
#define An 49

// Workspace layout (floats):
//   cv : Bn*Kn*An = 614656   @ 0
//   cg : Bn*Tn*An = 802816   @ 614656
//   cs : Bn*Tn*An = 802816   @ 1417472
#define WS_CV 0
#define WS_CG 614656
#define WS_CS 1417472

// Output layout (floats):
//   c_hat : Bn*Tn*Hn = 8388608 @ 0
//   alpha : Bn*Tn*Kn = 802816  @ 8388608
//   beta  : Bn*Tn    = 16384   @ 9191424
#define OUT_ALPHA 8388608
#define OUT_BETA  9191424

typedef __attribute__((ext_vector_type(8))) short short8;
typedef __attribute__((ext_vector_type(4))) short short4v;
typedef __attribute__((ext_vector_type(4))) float f32x4;

#define WLDS 520   // LDS row stride in bf16 elems: 512 + 8 pad (1040 B -> +4 bank shift/row)

__device__ __forceinline__ short bfc(float x) {
    __hip_bfloat16 h = __float2bfloat16(x);
    return __builtin_bit_cast(short, h);
}

__device__ __forceinline__ float fast_tanh(float x) {
    // tanh(x) = 1 - 2/(exp(2x)+1); saturates correctly for large |x|
    float e = __expf(2.0f * x);
    return 1.0f - 2.0f / (e + 1.0f);
}

// ---------------------------------------------------------------------------
// Kernel 1: three per-batch GEMMs vs H=512 via bf16 MFMA.
//   part 0: cv[b][k][a] = sum_h V[b,k,h]   * Wv[a,h]   (R=49)
//   part 1: cg[b][t][a] = sum_h h_t[b,t,h] * Wg[a,h]   (R=64)
//   part 2: cs[b][t][a] = sum_h s_t[b,t,h] * Ws[a,h]   (R=64)
// 256 threads = 4 waves; wave w computes rows 16w..16w+15 x all 64 col slots
// (4 tiles of 16x16), K=512 in 16 steps of 32.
// Fragment layouts (mfma_f32_16x16x32_bf16):
//   A: row = lane&15, k = (lane>>4)*8 + j (8 contiguous)  -> direct K-major load
//   B: col = lane&15, k = same                            -> direct K-major load
//   C: col = lane&15, row = (lane>>4)*4 + reg             [m89-verified]
// ---------------------------------------------------------------------------
__global__ __launch_bounds__(256) void gemm3_mfma(
    const float* __restrict__ V, const float* __restrict__ h_t,
    const float* __restrict__ s_t, const float* __restrict__ Wv,
    const float* __restrict__ Wg, const float* __restrict__ Ws,
    float* __restrict__ ws)
{
    const int b = blockIdx.x;
    const int part = blockIdx.y;

    const float* A;
    const float* W;
    float* out;
    int R;
    if (part == 0)      { A = V   + (size_t)b*Kn*Hn; W = Wv; out = ws + WS_CV + (size_t)b*Kn*An; R = Kn; }
    else if (part == 1) { A = h_t + (size_t)b*Tn*Hn; W = Wg; out = ws + WS_CG + (size_t)b*Tn*An; R = Tn; }
    else                { A = s_t + (size_t)b*Tn*Hn; W = Ws; out = ws + WS_CS + (size_t)b*Tn*An; R = Tn; }

    __shared__ short Wl[Kn * WLDS];   // 49 rows x 520 bf16 = 50.96 KB

    const int tid = threadIdx.x;

    // Stage W -> bf16 LDS (49*128 float4 chunks)
    for (int i = tid; i < Kn * 128; i += 256) {
        const int row = i >> 7;
        const int c4  = (i & 127) << 2;
        float4 v = *(const float4*)(W + (size_t)row * Hn + c4);
        short4v s;
        s.x = bfc(v.x); s.y = bfc(v.y); s.z = bfc(v.z); s.w = bfc(v.w);
        *(short4v*)(&Wl[row * WLDS + c4]) = s;
    }
    __syncthreads();

    const int wave = tid >> 6;
    const int lane = tid & 63;
    const int l15  = lane & 15;
    const int kgrp = lane >> 4;        // 0..3
    const int koff = kgrp * 8;

    const int r0 = wave * 16;
    int arow = r0 + l15; if (arow >= R) arow = R - 1;   // clamp (masked at write)
    const float* Ap = A + (size_t)arow * Hn + koff;

    int brow[4];
    #pragma unroll
    for (int ct = 0; ct < 4; ++ct) {
        int r = ct * 16 + l15;
        brow[ct] = (r < Kn) ? r : (Kn - 1);            // clamp (masked at write)
    }

    f32x4 acc[4] = {{0,0,0,0},{0,0,0,0},{0,0,0,0},{0,0,0,0}};

    for (int ks = 0; ks < 16; ++ks) {
        float4 a0 = *(const float4*)(Ap + ks * 32);
        float4 a1 = *(const float4*)(Ap + ks * 32 + 4);
        short8 af;
        af[0] = bfc(a0.x); af[1] = bfc(a0.y); af[2] = bfc(a0.z); af[3] = bfc(a0.w);
        af[4] = bfc(a1.x); af[5] = bfc(a1.y); af[6] = bfc(a1.z); af[7] = bfc(a1.w);
        #pragma unroll
        for (int ct = 0; ct < 4; ++ct) {
            short8 bfr = *(const short8*)(&Wl[brow[ct] * WLDS + koff + ks * 32]);
            acc[ct] = __builtin_amdgcn_mfma_f32_16x16x32_bf16(af, bfr, acc[ct], 0, 0, 0);
        }
    }

    #pragma unroll
    for (int ct = 0; ct < 4; ++ct) {
        const int a = ct * 16 + l15;
        if (a >= An) continue;
        #pragma unroll
        for (int i = 0; i < 4; ++i) {
            const int k = r0 + kgrp * 4 + i;
            if (k < R) out[(size_t)k * An + a] = acc[ct][i];
        }
    }
}

// ---------------------------------------------------------------------------
// Kernel 2: fused tanh-score + softmax + c_t + c_hat per (b, 16-row t-tile).
// grid = 1024 blocks (256 b * 4 tiles), 256 threads (4 waves).
// ---------------------------------------------------------------------------
#define TT 16
__global__ __launch_bounds__(256) void fused_kernel(
    const float* __restrict__ V, const float* __restrict__ s_t,
    const float* __restrict__ Wh, const float* __restrict__ ws,
    float* __restrict__ out)
{
    const int bid = blockIdx.x;
    const int b  = bid >> 2;
    const int t0 = (bid & 3) * TT;

    __shared__ float cv[Kn][Kn];   // stride 49 (odd) -> conflict-benign
    __shared__ float gl[TT][Kn];
    __shared__ float cl[TT][Kn];
    __shared__ float wh[Kn];
    __shared__ float zl[TT][Kn + 1];
    __shared__ float al[TT][Kn];
    __shared__ float bl[TT];

    const int tid = threadIdx.x;

    // stage cv[b], cg rows, cs rows, Wh
    {
        const float* cvg = ws + WS_CV + (size_t)b * Kn * An;
        float* cvf = &cv[0][0];
        for (int i = tid; i < Kn * An; i += 256) cvf[i] = cvg[i];
        const float* cgg = ws + WS_CG + ((size_t)b * Tn + t0) * An;
        const float* csg = ws + WS_CS + ((size_t)b * Tn + t0) * An;
        float* gf = &gl[0][0];
        float* cf = &cl[0][0];
        for (int i = tid; i < TT * An; i += 256) { gf[i] = cgg[i]; cf[i] = csg[i]; }
        if (tid < An) wh[tid] = Wh[tid];
    }
    __syncthreads();

    // z phase: TT*49 (t,k) scores + TT extended scores = 800 items
    for (int idx = tid; idx < TT * Kn + TT; idx += 256) {
        if (idx < TT * Kn) {
            const int tt = idx / Kn;
            const int k  = idx % Kn;
            float acc = 0.f;
            #pragma unroll 7
            for (int a = 0; a < Kn; ++a)
                acc += fast_tanh(gl[tt][a] + cv[k][a]) * wh[a];
            zl[tt][k] = acc;
        } else {
            const int tt = idx - TT * Kn;
            float acc = 0.f;
            #pragma unroll 7
            for (int a = 0; a < Kn; ++a)
                acc += fast_tanh(gl[tt][a] + cl[tt][a]) * wh[a];
            zl[tt][Kn] = acc;
        }
    }
    __syncthreads();

    // softmax: wave w handles rows 4w..4w+3
    {
        const int w    = tid >> 6;
        const int lane = tid & 63;
        for (int rr = 0; rr < 4; ++rr) {
            const int row = w * 4 + rr;
            float v = (lane < Kn) ? zl[row][lane] : -1e30f;
            float m = v;
            #pragma unroll
            for (int o = 32; o; o >>= 1) m = fmaxf(m, __shfl_xor(m, o, 64));
            float e = (lane < Kn) ? __expf(v - m) : 0.f;
            float s = e;
            #pragma unroll
            for (int o = 32; o; o >>= 1) s += __shfl_xor(s, o, 64);
            const float ze  = zl[row][Kn];
            const float m2  = fmaxf(m, ze);
            const float eze = __expf(ze - m2);
            const float denom = s * __expf(m - m2) + eze;
            const float beta  = eze / denom;
            if (lane < Kn) {
                const float a = e / s;
                al[row][lane] = a;
                out[OUT_ALPHA + ((size_t)(b * Tn + t0 + row)) * Kn + lane] = a;
            }
            if (lane == 0) {
                bl[row] = beta;
                out[OUT_BETA + (b * Tn + t0 + row)] = beta;
            }
        }
    }
    __syncthreads();

    // c_t + c_hat: tt = tid/16 (16 rows), 16-lane group covers H via 8 float4
    {
        const int tt  = tid >> 4;
        const int l16 = tid & 15;
        const float* vb = V + (size_t)b * Kn * Hn;
        float4 acc[8] = {};
        for (int k = 0; k < Kn; ++k) {
            const float ak = al[tt][k];
            const float4* vr = (const float4*)(vb + (size_t)k * Hn);
            #pragma unroll
            for (int j = 0; j < 8; ++j) {
                float4 vv = vr[l16 + 16 * j];
                acc[j].x += ak * vv.x; acc[j].y += ak * vv.y;
                acc[j].z += ak * vv.z; acc[j].w += ak * vv.w;
            }
        }
        const float beta = bl[tt];
        const float omb  = 1.f - beta;
        const float4* sr = (const float4*)(s_t + ((size_t)b * Tn + t0 + tt) * Hn);
        float4* orow = (float4*)(out + ((size_t)b * Tn + t0 + tt) * Hn);
        #pragma unroll
        for (int j = 0; j < 8; ++j) {
            float4 sv = sr[l16 + 16 * j];
            float4 o;
            o.x = beta * sv.x + omb * acc[j].x;
            o.y = beta * sv.y + omb * acc[j].y;
            o.z = beta * sv.z + omb * acc[j].z;
            o.w = beta * sv.w + omb * acc[j].w;
            orow[l16 + 16 * j] = o;
        }
    }
}

extern "C" void kernel_launch(void* const* d_in, const int* in_sizes, int n_in,
                              void* d_out, int out_size, void* d_ws, size_t ws_size,
                              hipStream_t stream)
{
    const float* V   = (const float*)d_in[0];
    const float* h_t = (const float*)d_in[1];
    const float* s_t = (const float*)d_in[2];
    const float* Wv  = (const float*)d_in[3];
    const float* Wg  = (const float*)d_in[4];
    const float* Ws  = (const float*)d_in[5];
    const float* Wh  = (const float*)d_in[6];
    float* out = (float*)d_out;
    float* ws  = (float*)d_ws;   // needs 8.9 MB

    dim3 g1(Bn, 3);
    gemm3_mfma<<<g1, 256, 0, stream>>>(V, h_t, s_t, Wv, Wg, Ws, ws);
    fused_kernel<<<Bn * 4, 256, 0, stream>>>(V, s_t, Wh, ws, out);
}

// Round 4
// 175.215 us; speedup vs baseline: 1.5125x; 1.2158x over previous
//
#include <hip/hip_runtime.h>
#include <hip/hip_bf16.h>
#include <math.h>

// Shapes
#define Bn 256
#define Tn 64
#define Kn 49
#define Hn 512
#define An 49

// Workspace layout (floats) — now stores e^{2x} of each content projection:
//   Ev = e^{2*cv} : Bn*Kn*An = 614656   @ 0
//   Eg = e^{2*cg} : Bn*Tn*An = 802816   @ 614656
//   Es = e^{2*cs} : Bn*Tn*An = 802816   @ 1417472
#define WS_EV 0
#define WS_EG 614656
#define WS_ES 1417472

// Output layout (floats):
//   c_hat : Bn*Tn*Hn = 8388608 @ 0
//   alpha : Bn*Tn*Kn = 802816  @ 8388608
//   beta  : Bn*Tn    = 16384   @ 9191424
#define OUT_ALPHA 8388608
#define OUT_BETA  9191424

typedef __attribute__((ext_vector_type(8))) short short8;
typedef __attribute__((ext_vector_type(4))) short short4v;
typedef __attribute__((ext_vector_type(4))) float f32x4;

#define WLDS 520   // gemm3 LDS row stride (bf16): 512 + 8 pad

__device__ __forceinline__ short bfc(float x) {
    __hip_bfloat16 h = __float2bfloat16(x);
    return __builtin_bit_cast(short, h);
}

// ---------------------------------------------------------------------------
// Kernel 1: three per-batch GEMMs vs H=512 via bf16 MFMA; epilogue stores
// e^{2*acc} (consumed algebraically by fused: tanh(x)=1-2/(e^{2x}+1)).
//   part 0: Ev[b][k][a] = exp(2 * sum_h V[b,k,h]   * Wv[a,h])   (R=49)
//   part 1: Eg[b][t][a] = exp(2 * sum_h h_t[b,t,h] * Wg[a,h])   (R=64)
//   part 2: Es[b][t][a] = exp(2 * sum_h s_t[b,t,h] * Ws[a,h])   (R=64)
// ---------------------------------------------------------------------------
__global__ __launch_bounds__(256) void gemm3_mfma(
    const float* __restrict__ V, const float* __restrict__ h_t,
    const float* __restrict__ s_t, const float* __restrict__ Wv,
    const float* __restrict__ Wg, const float* __restrict__ Ws,
    float* __restrict__ ws)
{
    const int b = blockIdx.x;
    const int part = blockIdx.y;

    const float* A;
    const float* W;
    float* out;
    int R;
    if (part == 0)      { A = V   + (size_t)b*Kn*Hn; W = Wv; out = ws + WS_EV + (size_t)b*Kn*An; R = Kn; }
    else if (part == 1) { A = h_t + (size_t)b*Tn*Hn; W = Wg; out = ws + WS_EG + (size_t)b*Tn*An; R = Tn; }
    else                { A = s_t + (size_t)b*Tn*Hn; W = Ws; out = ws + WS_ES + (size_t)b*Tn*An; R = Tn; }

    __shared__ short Wl[Kn * WLDS];   // 49 x 520 bf16 = 50.96 KB

    const int tid = threadIdx.x;

    // Stage W -> bf16 LDS
    for (int i = tid; i < Kn * 128; i += 256) {
        const int row = i >> 7;
        const int c4  = (i & 127) << 2;
        float4 v = *(const float4*)(W + (size_t)row * Hn + c4);
        short4v s;
        s.x = bfc(v.x); s.y = bfc(v.y); s.z = bfc(v.z); s.w = bfc(v.w);
        *(short4v*)(&Wl[row * WLDS + c4]) = s;
    }
    __syncthreads();

    const int wave = tid >> 6;
    const int lane = tid & 63;
    const int l15  = lane & 15;
    const int kgrp = lane >> 4;        // 0..3
    const int koff = kgrp * 8;

    const int r0 = wave * 16;
    int arow = r0 + l15; if (arow >= R) arow = R - 1;   // clamp (masked at write)
    const float* Ap = A + (size_t)arow * Hn + koff;

    int brow[4];
    #pragma unroll
    for (int ct = 0; ct < 4; ++ct) {
        int r = ct * 16 + l15;
        brow[ct] = (r < Kn) ? r : (Kn - 1);            // clamp (masked at write)
    }

    f32x4 acc[4] = {{0,0,0,0},{0,0,0,0},{0,0,0,0},{0,0,0,0}};

    for (int ks = 0; ks < 16; ++ks) {
        float4 a0 = *(const float4*)(Ap + ks * 32);
        float4 a1 = *(const float4*)(Ap + ks * 32 + 4);
        short8 af;
        af[0] = bfc(a0.x); af[1] = bfc(a0.y); af[2] = bfc(a0.z); af[3] = bfc(a0.w);
        af[4] = bfc(a1.x); af[5] = bfc(a1.y); af[6] = bfc(a1.z); af[7] = bfc(a1.w);
        #pragma unroll
        for (int ct = 0; ct < 4; ++ct) {
            short8 bfr = *(const short8*)(&Wl[brow[ct] * WLDS + koff + ks * 32]);
            acc[ct] = __builtin_amdgcn_mfma_f32_16x16x32_bf16(af, bfr, acc[ct], 0, 0, 0);
        }
    }

    #pragma unroll
    for (int ct = 0; ct < 4; ++ct) {
        const int a = ct * 16 + l15;
        if (a >= An) continue;
        #pragma unroll
        for (int i = 0; i < 4; ++i) {
            const int k = r0 + kgrp * 4 + i;
            if (k < R) out[(size_t)k * An + a] = __expf(2.0f * acc[ct][i]);
        }
    }
}

// ---------------------------------------------------------------------------
// Kernel 2: fused score + softmax + c_t + c_hat per (b, 16-row t-tile).
// grid = 1024 blocks (256 b * 4 tiles), 256 threads (4 waves).
//   z[t][k]  = Swh - 2 * sum_a wh[a] / (Eg[t][a]*Ev[k][a] + 1)
//   z_ext[t] = Swh - 2 * sum_a wh[a] / (Eg[t][a]*Es[t][a] + 1)
// c_t phase: thread owns float2 h-slice for all 16 rows (coalesced V reads,
// panel read once per block).
// ---------------------------------------------------------------------------
#define TT 16
#define AP 52   // padded A stride (multiple of 4; pads: wh=0, E*=1)

__global__ __launch_bounds__(256) void fused_kernel(
    const float* __restrict__ V, const float* __restrict__ s_t,
    const float* __restrict__ Wh, const float* __restrict__ ws,
    float* __restrict__ out)
{
    const int bid = blockIdx.x;
    const int b  = bid >> 2;
    const int t0 = (bid & 3) * TT;

    __shared__ float EvL[Kn * AP];     // 10.2 KB
    __shared__ float EgL[TT * AP];     // 3.3 KB
    __shared__ float EcL[TT * AP];     // 3.3 KB  (= Eg*Es)
    __shared__ float whL[AP];
    __shared__ float zl[TT][Kn + 1];
    __shared__ float al[TT][AP];       // alpha, pads zeroed
    __shared__ float bl[TT];
    __shared__ float swhL;

    const int tid = threadIdx.x;

    // ---- stage ----
    {
        const float* evg = ws + WS_EV + (size_t)b * Kn * An;
        for (int i = tid; i < Kn * An; i += 256) {
            const int r = i / An;
            const int c = i - r * An;
            EvL[r * AP + c] = evg[i];
        }
        const float* egg = ws + WS_EG + ((size_t)b * Tn + t0) * An;
        const float* esg = ws + WS_ES + ((size_t)b * Tn + t0) * An;
        for (int i = tid; i < TT * An; i += 256) {
            const int r = i / An;
            const int c = i - r * An;
            const float eg = egg[i];
            EgL[r * AP + c] = eg;
            EcL[r * AP + c] = eg * esg[i];
        }
        // pads (must be finite: product enters rcp; wh pad=0 kills contribution)
        if (tid < Kn * 3) {
            const int r = tid / 3;
            const int c = An + (tid - r * 3);
            EvL[r * AP + c] = 1.f;
        }
        if (tid >= 64 && tid < 64 + TT * 3) {
            const int j = tid - 64;
            const int r = j / 3;
            const int c = An + (j - r * 3);
            EgL[r * AP + c] = 1.f;
            EcL[r * AP + c] = 1.f;
        }
        float whv = 0.f;
        if (tid < AP) { whv = (tid < An) ? Wh[tid] : 0.f; whL[tid] = whv; }
        if (tid < 64) {    // wave 0 computes Swh
            float sv = whv;
            #pragma unroll
            for (int o = 32; o; o >>= 1) sv += __shfl_xor(sv, o, 64);
            if (tid == 0) swhL = sv;
        }
    }
    __syncthreads();

    const float swh = swhL;

    // ---- z phase: 784 z_t + 16 z_ext ----
    for (int idx = tid; idx < TT * Kn + TT; idx += 256) {
        if (idx < TT * Kn) {
            const int tt = idx / Kn;
            const int k  = idx - tt * Kn;
            const float4* eg4 = (const float4*)&EgL[tt * AP];
            const float4* ev4 = (const float4*)&EvL[k * AP];
            const float4* wh4 = (const float4*)whL;
            float acc = 0.f;
            #pragma unroll
            for (int j = 0; j < 13; ++j) {
                const float4 g = eg4[j], v = ev4[j], w = wh4[j];
                acc += w.x * __builtin_amdgcn_rcpf(g.x * v.x + 1.f);
                acc += w.y * __builtin_amdgcn_rcpf(g.y * v.y + 1.f);
                acc += w.z * __builtin_amdgcn_rcpf(g.z * v.z + 1.f);
                acc += w.w * __builtin_amdgcn_rcpf(g.w * v.w + 1.f);
            }
            zl[tt][k] = swh - 2.f * acc;
        } else {
            const int tt = idx - TT * Kn;
            const float4* ec4 = (const float4*)&EcL[tt * AP];
            const float4* wh4 = (const float4*)whL;
            float acc = 0.f;
            #pragma unroll
            for (int j = 0; j < 13; ++j) {
                const float4 c = ec4[j], w = wh4[j];
                acc += w.x * __builtin_amdgcn_rcpf(c.x + 1.f);
                acc += w.y * __builtin_amdgcn_rcpf(c.y + 1.f);
                acc += w.z * __builtin_amdgcn_rcpf(c.z + 1.f);
                acc += w.w * __builtin_amdgcn_rcpf(c.w + 1.f);
            }
            zl[tt][Kn] = swh - 2.f * acc;
        }
    }
    __syncthreads();

    // ---- softmax: wave w handles rows 4w..4w+3 ----
    {
        const int w    = tid >> 6;
        const int lane = tid & 63;
        #pragma unroll
        for (int rr = 0; rr < 4; ++rr) {
            const int row = w * 4 + rr;
            float v = (lane < Kn) ? zl[row][lane] : -1e30f;
            float m = v;
            #pragma unroll
            for (int o = 32; o; o >>= 1) m = fmaxf(m, __shfl_xor(m, o, 64));
            float e = (lane < Kn) ? __expf(v - m) : 0.f;
            float s = e;
            #pragma unroll
            for (int o = 32; o; o >>= 1) s += __shfl_xor(s, o, 64);
            const float ze  = zl[row][Kn];
            const float m2  = fmaxf(m, ze);
            const float eze = __expf(ze - m2);
            const float denom = s * __expf(m - m2) + eze;
            const float beta  = eze * __builtin_amdgcn_rcpf(denom);
            const float a = e * __builtin_amdgcn_rcpf(s);
            if (lane < AP) al[row][lane] = a;   // lanes 49..51 write 0 (e=0)
            if (lane < Kn)
                out[OUT_ALPHA + ((size_t)(b * Tn + t0 + row)) * Kn + lane] = a;
            if (lane == 0) {
                bl[row] = beta;
                out[OUT_BETA + (b * Tn + t0 + row)] = beta;
            }
        }
    }
    __syncthreads();

    // ---- c_t + c_hat: thread owns float2 h-slice (h = 2*tid) for all 16 rows
    {
        const float2* vb2 = (const float2*)(V + (size_t)b * Kn * Hn);
        float2 acc2[TT];
        #pragma unroll
        for (int r = 0; r < TT; ++r) { acc2[r].x = 0.f; acc2[r].y = 0.f; }

        for (int j = 0; j < 13; ++j) {
            const int k0 = j * 4;
            float2 vv[4];
            #pragma unroll
            for (int u = 0; u < 4; ++u) {
                int kk = k0 + u; kk = (kk > Kn - 1) ? (Kn - 1) : kk;  // al pad=0 masks
                vv[u] = vb2[(size_t)kk * (Hn / 2) + tid];
            }
            #pragma unroll
            for (int r = 0; r < TT; ++r) {
                const float4 a4 = *(const float4*)&al[r][k0];   // broadcast b128
                acc2[r].x += a4.x * vv[0].x + a4.y * vv[1].x + a4.z * vv[2].x + a4.w * vv[3].x;
                acc2[r].y += a4.x * vv[0].y + a4.y * vv[1].y + a4.z * vv[2].y + a4.w * vv[3].y;
            }
        }

        #pragma unroll
        for (int r = 0; r < TT; ++r) {
            const float beta = bl[r];
            const float omb  = 1.f - beta;
            const size_t row = (size_t)(b * Tn + t0 + r) * Hn;
            const float2 sv = *(const float2*)(s_t + row + 2 * tid);
            float2 o;
            o.x = beta * sv.x + omb * acc2[r].x;
            o.y = beta * sv.y + omb * acc2[r].y;
            *(float2*)(out + row + 2 * tid) = o;
        }
    }
}

extern "C" void kernel_launch(void* const* d_in, const int* in_sizes, int n_in,
                              void* d_out, int out_size, void* d_ws, size_t ws_size,
                              hipStream_t stream)
{
    const float* V   = (const float*)d_in[0];
    const float* h_t = (const float*)d_in[1];
    const float* s_t = (const float*)d_in[2];
    const float* Wv  = (const float*)d_in[3];
    const float* Wg  = (const float*)d_in[4];
    const float* Ws  = (const float*)d_in[5];
    const float* Wh  = (const float*)d_in[6];
    float* out = (float*)d_out;
    float* ws  = (float*)d_ws;   // needs 8.9 MB

    dim3 g1(Bn, 3);
    gemm3_mfma<<<g1, 256, 0, stream>>>(V, h_t, s_t, Wv, Wg, Ws, ws);
    fused_kernel<<<Bn * 4, 256, 0, stream>>>(V, s_t, Wh, ws, out);
}